// Round 3
// baseline (50.309 us; speedup 1.0000x reference)
//
#include <hip/hip_runtime.h>
#include <math.h>

#define FFT_N   4096
#define NT      256
// Padded LDS index: +1 float2 per 16 keeps every stage's strided access at
// the wave64 b64 floor (even bank-pair coverage, no above-floor conflicts).
#define PHYS(i) ((i) + ((i) >> 4))
#define LDS_SZ  (FFT_N + FFT_N / 16)

__device__ __forceinline__ float2 cadd(float2 a, float2 b) { return make_float2(a.x + b.x, a.y + b.y); }
__device__ __forceinline__ float2 csub(float2 a, float2 b) { return make_float2(a.x - b.x, a.y - b.y); }
__device__ __forceinline__ float2 cmul(float2 a, float2 b) { return make_float2(a.x * b.x - a.y * b.y, a.x * b.y + a.y * b.x); }

// In-place 4-point DFT (w4 = -i).
__device__ __forceinline__ void dft4(float2& a, float2& b, float2& c, float2& d) {
    float2 t0 = cadd(a, c);
    float2 t1 = csub(a, c);
    float2 t2 = cadd(b, d);
    float2 t3 = make_float2(b.y - d.y, d.x - b.x);  // -i*(b-d)
    a = cadd(t0, t2);
    b = cadd(t1, t3);
    c = csub(t0, t2);
    d = csub(t1, t3);
}

// 16-point DFT in registers via radix-4 x radix-4.
// Input v[r] = c_r. Output DFT16[q1 + 4*q2] lands in v[4*q1 + q2]
// (caller maps q -> reg = ((q&3)<<2)|(q>>2)).
__device__ __forceinline__ void dft16(float2 v[16]) {
    #pragma unroll
    for (int r1 = 0; r1 < 4; ++r1)
        dft4(v[r1], v[r1 + 4], v[r1 + 8], v[r1 + 12]);

    const float C1 = 0.92387953251128675613f;  // cos(pi/8)
    const float S1 = 0.38268343236508977173f;  // sin(pi/8)
    const float R2 = 0.70710678118654752440f;  // sqrt(2)/2
    v[5]  = cmul(v[5],  make_float2( C1, -S1));   // w16^1
    v[9]  = cmul(v[9],  make_float2( R2, -R2));   // w16^2
    v[13] = cmul(v[13], make_float2( S1, -C1));   // w16^3
    v[6]  = cmul(v[6],  make_float2( R2, -R2));   // w16^2
    v[10] = make_float2(v[10].y, -v[10].x);       // w16^4 = -i
    v[14] = cmul(v[14], make_float2(-R2, -R2));   // w16^6
    v[7]  = cmul(v[7],  make_float2( S1, -C1));   // w16^3
    v[11] = cmul(v[11], make_float2(-R2, -R2));   // w16^6
    v[15] = cmul(v[15], make_float2(-C1,  S1));   // w16^9
    #pragma unroll
    for (int q1 = 0; q1 < 4; ++q1)
        dft4(v[4 * q1], v[4 * q1 + 1], v[4 * q1 + 2], v[4 * q1 + 3]);
}

// Store one radix-16 Stockham stage's outputs (with inter-stage twiddle via
// recurrence w_q = w_{q-1} * w1 — 1 sincos + 14 cmul instead of 15 sincos).
template <int M, bool TW>
__device__ __forceinline__ void store_stage(float2* buf, int tid, float2 v[16]) {
    const int j = tid / M;
    const int k = tid % M;
    const int obase = j * 16 * M + k;
    if (TW) {
        float sn, cs;
        __sincosf((float)j * (-6.28318530717958647692f * (float)M / (float)FFT_N), &sn, &cs);
        const float2 w1 = make_float2(cs, sn);
        float2 wq = w1;
        buf[PHYS(obase)] = v[0];
        #pragma unroll
        for (int q = 1; q < 16; ++q) {
            const int reg = ((q & 3) << 2) | (q >> 2);
            buf[PHYS(obase + q * M)] = cmul(v[reg], wq);
            wq = cmul(wq, w1);
        }
    } else {
        #pragma unroll
        for (int q = 0; q < 16; ++q) {
            const int reg = ((q & 3) << 2) | (q >> 2);
            buf[PHYS(obase + q * M)] = v[reg];
        }
    }
}

__device__ __forceinline__ void load_stage(const float2* buf, int tid, float2 v[16]) {
    #pragma unroll
    for (int r = 0; r < 16; ++r) v[r] = buf[PHYS(tid + 256 * r)];
}

// One block per PAIR of windows: z = x1 + i*x2, one 4096-pt complex FFT,
// unpack |F1|^2, |F2|^2 via conjugate symmetry. Stage 1's register gather
// (z[tid + 256*r]) is lane-coalesced in global memory, so it loads directly
// from HBM — no LDS staging pass, no staging barriers.
__global__ __launch_bounds__(NT) void spec_fft_kernel(const float* __restrict__ x,
                                                      float* __restrict__ out) {
    __shared__ float2 buf[LDS_SZ];
    const int tid = threadIdx.x;
    const size_t base = (size_t)blockIdx.x * (2 * FFT_N);
    const float* __restrict__ x1 = x + base + tid;
    const float* __restrict__ x2 = x + base + FFT_N + tid;

    float2 v[16];
    #pragma unroll
    for (int r = 0; r < 16; ++r)
        v[r] = make_float2(x1[256 * r], x2[256 * r]);

    // Stage 1 (M=1)
    dft16(v);
    store_stage<1, true>(buf, tid, v);
    __syncthreads();

    // Stage 2 (M=16)
    load_stage(buf, tid, v);
    __syncthreads();
    dft16(v);
    store_stage<16, true>(buf, tid, v);
    __syncthreads();

    // Stage 3 (M=256), no twiddles (j==0 would be the only factor group)
    load_stage(buf, tid, v);
    __syncthreads();
    dft16(v);
    store_stage<256, false>(buf, tid, v);
    __syncthreads();

    // Epilogue: F1(k) = (Z(k)+conj(Z(N-k)))/2, F2(k) = (Z(k)-conj(Z(N-k)))/(2i)
    float* __restrict__ o1 = out + base;
    float* __restrict__ o2 = out + base + FFT_N;
    #pragma unroll
    for (int it = 0; it < 4; ++it) {
        int idx = tid + 256 * it;
        float4 r1, r2;
        #pragma unroll
        for (int c = 0; c < 4; ++c) {
            int k = 4 * idx + c;
            float2 zk = buf[PHYS(k)];
            float2 zn = buf[PHYS((FFT_N - k) & (FFT_N - 1))];
            float e1r = zk.x + zn.x, e1i = zk.y - zn.y;   // 2*F1
            float e2r = zk.x - zn.x, e2i = zk.y + zn.y;   // 2i*F2 (same magnitude)
            (&r1.x)[c] = 0.25f * (e1r * e1r + e1i * e1i);
            (&r2.x)[c] = 0.25f * (e2r * e2r + e2i * e2i);
        }
        ((float4*)o1)[idx] = r1;
        ((float4*)o2)[idx] = r2;
    }
}

extern "C" void kernel_launch(void* const* d_in, const int* in_sizes, int n_in,
                              void* d_out, int out_size, void* d_ws, size_t ws_size,
                              hipStream_t stream) {
    const float* x = (const float*)d_in[0];
    float* out = (float*)d_out;
    const int B = in_sizes[0] / FFT_N;  // 8192
    spec_fft_kernel<<<B / 2, NT, 0, stream>>>(x, out);
}

// Round 4
// 48.228 us; speedup vs baseline: 1.0432x; 1.0432x over previous
//
#include <hip/hip_runtime.h>
#include <math.h>

#define FFT_N   4096
#define NT      256
// Padded LDS index: +1 float2 per 16 keeps every stage's strided access at
// the wave64 b64 floor (even bank-pair coverage, no above-floor conflicts).
#define PHYS(i) ((i) + ((i) >> 4))
#define LDS_SZ  (FFT_N + FFT_N / 16)

__device__ __forceinline__ float2 cadd(float2 a, float2 b) { return make_float2(a.x + b.x, a.y + b.y); }
__device__ __forceinline__ float2 csub(float2 a, float2 b) { return make_float2(a.x - b.x, a.y - b.y); }
__device__ __forceinline__ float2 cmul(float2 a, float2 b) { return make_float2(a.x * b.x - a.y * b.y, a.x * b.y + a.y * b.x); }

// In-place 4-point DFT (w4 = -i).
__device__ __forceinline__ void dft4(float2& a, float2& b, float2& c, float2& d) {
    float2 t0 = cadd(a, c);
    float2 t1 = csub(a, c);
    float2 t2 = cadd(b, d);
    float2 t3 = make_float2(b.y - d.y, d.x - b.x);  // -i*(b-d)
    a = cadd(t0, t2);
    b = cadd(t1, t3);
    c = csub(t0, t2);
    d = csub(t1, t3);
}

// 16-point DFT in registers via radix-4 x radix-4.
// Input v[r] = c_r. Output DFT16[q1 + 4*q2] lands in v[4*q1 + q2]
// (caller maps q -> reg = ((q&3)<<2)|(q>>2)).
__device__ __forceinline__ void dft16(float2 v[16]) {
    #pragma unroll
    for (int r1 = 0; r1 < 4; ++r1)
        dft4(v[r1], v[r1 + 4], v[r1 + 8], v[r1 + 12]);

    const float C1 = 0.92387953251128675613f;  // cos(pi/8)
    const float S1 = 0.38268343236508977173f;  // sin(pi/8)
    const float R2 = 0.70710678118654752440f;  // sqrt(2)/2
    v[5]  = cmul(v[5],  make_float2( C1, -S1));   // w16^1
    v[9]  = cmul(v[9],  make_float2( R2, -R2));   // w16^2
    v[13] = cmul(v[13], make_float2( S1, -C1));   // w16^3
    v[6]  = cmul(v[6],  make_float2( R2, -R2));   // w16^2
    v[10] = make_float2(v[10].y, -v[10].x);       // w16^4 = -i
    v[14] = cmul(v[14], make_float2(-R2, -R2));   // w16^6
    v[7]  = cmul(v[7],  make_float2( S1, -C1));   // w16^3
    v[11] = cmul(v[11], make_float2(-R2, -R2));   // w16^6
    v[15] = cmul(v[15], make_float2(-C1,  S1));   // w16^9
    #pragma unroll
    for (int q1 = 0; q1 < 4; ++q1)
        dft4(v[4 * q1], v[4 * q1 + 1], v[4 * q1 + 2], v[4 * q1 + 3]);
}

// Stage store with inter-stage twiddles built log-depth (dep chain ~4 deep,
// not a 15-long serial recurrence): w2=w1^2, w4=w2^2, w8=w4^2, rest are
// single products of two already-computed factors.
template <int M>
__device__ __forceinline__ void store_stage_tw(float2* buf, int tid, float2 v[16]) {
    const int j = tid / M;
    const int k = tid % M;
    const int obase = j * 16 * M + k;
    float sn, cs;
    __sincosf((float)j * (-6.28318530717958647692f * (float)M / (float)FFT_N), &sn, &cs);
    float2 w[16];
    w[1]  = make_float2(cs, sn);
    w[2]  = cmul(w[1], w[1]);
    w[3]  = cmul(w[2], w[1]);
    w[4]  = cmul(w[2], w[2]);
    w[5]  = cmul(w[4], w[1]);
    w[6]  = cmul(w[4], w[2]);
    w[7]  = cmul(w[4], w[3]);
    w[8]  = cmul(w[4], w[4]);
    w[9]  = cmul(w[8], w[1]);
    w[10] = cmul(w[8], w[2]);
    w[11] = cmul(w[8], w[3]);
    w[12] = cmul(w[8], w[4]);
    w[13] = cmul(w[8], w[5]);
    w[14] = cmul(w[8], w[6]);
    w[15] = cmul(w[8], w[7]);
    buf[PHYS(obase)] = v[0];
    #pragma unroll
    for (int q = 1; q < 16; ++q) {
        const int reg = ((q & 3) << 2) | (q >> 2);
        buf[PHYS(obase + q * M)] = cmul(v[reg], w[q]);
    }
}

__device__ __forceinline__ void load_stage(const float2* buf, int tid, float2 v[16]) {
    #pragma unroll
    for (int r = 0; r < 16; ++r) v[r] = buf[PHYS(tid + 256 * r)];
}

// One block per PAIR of windows: z = x1 + i*x2, one 4096-pt complex FFT,
// unpack |F1|^2, |F2|^2 via conjugate symmetry. Stage 1's register gather
// (z[tid + 256*r]) is lane-coalesced in global memory -> load direct from HBM.
// Stage 3 fuses the epilogue: Z(k) stays in registers, only the conjugate
// mirror Z(N-k) comes from LDS; outputs stream out via nontemporal stores so
// the 134 MB write stream doesn't evict the L3-resident input.
__global__ __launch_bounds__(NT) void spec_fft_kernel(const float* __restrict__ x,
                                                      float* __restrict__ out) {
    __shared__ float2 buf[LDS_SZ];
    const int tid = threadIdx.x;
    const size_t base = (size_t)blockIdx.x * (2 * FFT_N);
    const float* __restrict__ x1 = x + base + tid;
    const float* __restrict__ x2 = x + base + FFT_N + tid;

    float2 v[16];
    #pragma unroll
    for (int r = 0; r < 16; ++r)
        v[r] = make_float2(x1[256 * r], x2[256 * r]);

    // Stage 1 (M=1)
    dft16(v);
    store_stage_tw<1>(buf, tid, v);
    __syncthreads();

    // Stage 2 (M=16)
    load_stage(buf, tid, v);
    __syncthreads();
    dft16(v);
    store_stage_tw<16>(buf, tid, v);
    __syncthreads();

    // Stage 3 (M=256): j==0 -> no twiddles. Thread tid ends holding
    // Z[tid + 256*q] in v[reg(q)]. Store to LDS only for the mirror reads.
    load_stage(buf, tid, v);
    __syncthreads();
    dft16(v);
    #pragma unroll
    for (int q = 0; q < 16; ++q) {
        const int reg = ((q & 3) << 2) | (q >> 2);
        buf[PHYS(tid + 256 * q)] = v[reg];
    }
    __syncthreads();

    // Fused epilogue: F1(k) = (Z(k)+conj(Z(N-k)))/2, F2(k) = (Z(k)-conj(Z(N-k)))/(2i)
    float* __restrict__ o1 = out + base;
    float* __restrict__ o2 = out + base + FFT_N;
    #pragma unroll
    for (int q = 0; q < 16; ++q) {
        const int reg = ((q & 3) << 2) | (q >> 2);
        const int k = tid + 256 * q;
        float2 zk = v[reg];
        float2 zn = buf[PHYS((FFT_N - k) & (FFT_N - 1))];
        float e1r = zk.x + zn.x, e1i = zk.y - zn.y;   // 2*F1
        float e2r = zk.x - zn.x, e2i = zk.y + zn.y;   // 2i*F2 (same magnitude)
        __builtin_nontemporal_store(0.25f * (e1r * e1r + e1i * e1i), o1 + k);
        __builtin_nontemporal_store(0.25f * (e2r * e2r + e2i * e2i), o2 + k);
    }
}

extern "C" void kernel_launch(void* const* d_in, const int* in_sizes, int n_in,
                              void* d_out, int out_size, void* d_ws, size_t ws_size,
                              hipStream_t stream) {
    const float* x = (const float*)d_in[0];
    float* out = (float*)d_out;
    const int B = in_sizes[0] / FFT_N;  // 8192
    spec_fft_kernel<<<B / 2, NT, 0, stream>>>(x, out);
}